// Round 10
// baseline (81.364 us; speedup 1.0000x reference)
//
#include <hip/hip_runtime.h>
#include <math.h>

typedef _Float16 v8h __attribute__((ext_vector_type(8)));
typedef float    v4f __attribute__((ext_vector_type(4)));

#define NB    32       // batch elements per block (two 16-row MFMA tiles per wave)
#define DSTR  264      // zh row stride in halves
#define WSTR  68       // wbuf/gbuf per-batch stride (floats)
#define EPSLN 1e-5f

struct KP {
  const float* Z[8];
  const float* A;
  const float *W0, *b0, *g0, *be0, *Wg0, *bg0;
  const float *b1, *g1, *be1, *bg1;
  const float *b2, *g2, *be2, *bg2;
  const float *bout;
  const _Float16 *WgT1, *WgT2, *WT1, *WT2, *WoT, *W0T;
  const float *stats;   // [8][17] analytic LN stats for layer0
  float* out;
};

// ---- combined weight conversion: dst[i][o][f] = (o<Osrc) ? src[i][f][o] : 0 (f16)
__device__ __forceinline__ void cvt_one(const float* __restrict__ src, _Float16* __restrict__ dst,
                                        int F, int Osrc, int Opad, int t) {
  const int f  = t % F;
  const int io = t / F;
  const int o  = io % Opad;
  const int i  = io / Opad;
  dst[t] = (o < Osrc) ? (_Float16)src[(i * F + f) * Osrc + o] : (_Float16)0.f;
}

#define E1 114688   // Wg1 -> WgT1 (F=1792, 7->8)
#define E2 57344    // Wg2 -> WgT2 (F=896, 7->8)
#define E3 4096     // Wout -> WoT (F=64, 5->8)
#define E4 262144   // W1 -> WT1 (F=256, 128)
#define E5 65536    // W2 -> WT2 (F=128, 64)
#define E6 65536    // W0 -> W0T [i][o][k<32], k<3 = W0[d=k][o]
#define NSTAT 136   // 8 nodes x 17 f32 stats

__global__ void cvt_all(const float* __restrict__ Wg1, const float* __restrict__ Wg2,
                        const float* __restrict__ Wout, const float* __restrict__ W1,
                        const float* __restrict__ W2, const float* __restrict__ W0,
                        const float* __restrict__ b0, _Float16* __restrict__ ws) {
  int t = blockIdx.x * 256 + threadIdx.x;
  if (t < E1) { cvt_one(Wg1, ws, 1792, 7, 8, t); return; }
  t -= E1;
  if (t < E2) { cvt_one(Wg2, ws + E1, 896, 7, 8, t); return; }
  t -= E2;
  if (t < E3) { cvt_one(Wout, ws + E1 + E2, 64, 5, 8, t); return; }
  t -= E3;
  if (t < E4) { cvt_one(W1, ws + E1 + E2 + E3, 256, 128, 128, t); return; }
  t -= E4;
  if (t < E5) { cvt_one(W2, ws + E1 + E2 + E3 + E4, 128, 64, 64, t); return; }
  t -= E5;
  if (t < E6) {   // W0T: t = (i*256 + o)*32 + k
    const int k = t & 31;
    const int o = (t >> 5) & 255;
    const int i = t >> 13;
    ws[E1 + E2 + E3 + E4 + E5 + t] = (k < 3) ? (_Float16)W0[(i * 3 + k) * 256 + o] : (_Float16)0.f;
    return;
  }
  t -= E6;
  if (t < NSTAT) {  // analytic LN stats for layer0: [i][17]
    float* sf = (float*)(ws + E1 + E2 + E3 + E4 + E5 + E6);
    const int i = t / 17, j = t % 17;
    float v = 0.f;
    if (j < 3) {                       // wbar_d
      for (int o = 0; o < 256; ++o) v += W0[(i * 3 + j) * 256 + o];
    } else if (j == 3) {               // bbar
      for (int o = 0; o < 256; ++o) v += b0[i * 256 + o];
    } else if (j < 13) {               // M[a][b] = (1/O) sum W_ao W_bo
      const int a = (j - 4) / 3, bb = (j - 4) % 3;
      for (int o = 0; o < 256; ++o)
        v += W0[(i * 3 + a) * 256 + o] * W0[(i * 3 + bb) * 256 + o];
    } else if (j < 16) {               // c_d = (1/O) sum W_do b_o
      const int d = j - 13;
      for (int o = 0; o < 256; ++o)
        v += W0[(i * 3 + d) * 256 + o] * b0[i * 256 + o];
    } else {                           // e = (1/O) sum b_o^2
      for (int o = 0; o < 256; ++o) { const float x = b0[i * 256 + o]; v += x * x; }
    }
    sf[t] = v * (1.f / 256.f);
  }
}

// One MFMA layer, M=2x16. Gate B-frags preloaded (gpre); dense ks=0 B-frags
// hoisted above gate; NPRE next-phase B-frags issued post-k-loop (fly during LN
// + barriers). wbuf cols of node i are same-wave -> no barrier after softmax.
template<int D, int O, int NPRE>
__device__ __forceinline__ void mfma_layer(
    _Float16* __restrict__ zh, float* __restrict__ wbuf, const float* __restrict__ gbuf,
    const v8h* gpre,
    const _Float16* __restrict__ WgT, const float* __restrict__ bg,
    const _Float16* __restrict__ WT, const float* __restrict__ bias,
    const float* __restrict__ g, const float* __restrict__ be,
    const _Float16* __restrict__ preBase, int preStride, v8h* pre,
    int i, int q, int r)
{
  constexpr int KS = D / 32;
  constexpr int NT = O / 16;

  const _Float16* WgB = WgT + (size_t)(i * 8 + r) * (7 * D) + q * 8;  // gate B rows
  const _Float16* WB  = WT  + (size_t)(i * O + r) * D + q * 8;        // dense B rows

  v8h dbf[NT];
  #pragma unroll
  for (int n = 0; n < NT; ++n) dbf[n] = *(const v8h*)(WB + (size_t)n * 16 * D);

  v8h gbf[7];
  #pragma unroll
  for (int nb = 0; nb < 7; ++nb) gbf[nb] = gpre[nb];

  // ---------------- gate: logits[32b x 16(7)], 4 independent chains ----------------
  v4f ca[2][2];
  #pragma unroll
  for (int mt = 0; mt < 2; ++mt)
    #pragma unroll
    for (int c = 0; c < 2; ++c) ca[mt][c] = (v4f){0.f,0.f,0.f,0.f};

  #pragma unroll
  for (int ks = 0; ks < KS; ++ks) {
    const int d0 = ks * 32 + q * 8;
    v8h gbn[7];
    if (ks + 1 < KS) {
      #pragma unroll
      for (int nb = 0; nb < 7; ++nb)
        gbn[nb] = *(const v8h*)(WgB + nb * D + (ks + 1) * 32);
    }
    #pragma unroll
    for (int nb = 0; nb < 7; ++nb) {
      const int nk = nb + (nb >= i);
      const v8h af0 = *(const v8h*)(zh + (nk * NB + r) * DSTR + d0);
      const v8h af1 = *(const v8h*)(zh + (nk * NB + 16 + r) * DSTR + d0);
      ca[0][nb & 1] = __builtin_amdgcn_mfma_f32_16x16x32_f16(af0, gbf[nb], ca[0][nb & 1], 0, 0, 0);
      ca[1][nb & 1] = __builtin_amdgcn_mfma_f32_16x16x32_f16(af1, gbf[nb], ca[1][nb & 1], 0, 0, 0);
    }
    if (ks + 1 < KS) {
      #pragma unroll
      for (int nb = 0; nb < 7; ++nb) gbf[nb] = gbn[nb];
    }
  }
  const v4f gacc[2] = { ca[0][0] + ca[0][1], ca[1][0] + ca[1][1] };

  // softmax over cols r<7 (16-lane groups), times input gates -> wbuf (same-wave cols)
  const float bgv = (r < 7) ? bg[i * 7 + r] : 0.f;
  #pragma unroll
  for (int mt = 0; mt < 2; ++mt) {
    #pragma unroll
    for (int reg = 0; reg < 4; ++reg) {
      const float v = gacc[mt][reg] + bgv;
      float m = (r < 7) ? v : -3.0e38f;
      #pragma unroll
      for (int mk = 1; mk < 16; mk <<= 1) m = fmaxf(m, __shfl_xor(m, mk, 16));
      const float e = (r < 7) ? __expf(v - m) : 0.f;
      float s = e;
      #pragma unroll
      for (int mk = 1; mk < 16; mk <<= 1) s += __shfl_xor(s, mk, 16);
      const int b = mt * 16 + q * 4 + reg;
      if (r < 7) wbuf[b * WSTR + i * 8 + r] = (e / s) * gbuf[b * WSTR + i * 8 + r];
    }
  }

  // ---------------- dense: h = (z_i + sum_k w_k z_nk) @ W_i + b ----------------
  v4f acc[2][NT];
  #pragma unroll
  for (int mt = 0; mt < 2; ++mt)
    #pragma unroll
    for (int n = 0; n < NT; ++n) acc[mt][n] = (v4f){0.f,0.f,0.f,0.f};

  _Float16 wh[2][7];
  #pragma unroll
  for (int mt = 0; mt < 2; ++mt)
    #pragma unroll
    for (int nb = 0; nb < 7; ++nb)
      wh[mt][nb] = (_Float16)wbuf[(mt * 16 + r) * WSTR + i * 8 + nb];

  #pragma unroll
  for (int ks = 0; ks < KS; ++ks) {
    const int d0 = ks * 32 + q * 8;
    v8h dbn[NT];
    if (ks + 1 < KS) {
      #pragma unroll
      for (int n = 0; n < NT; ++n)
        dbn[n] = *(const v8h*)(WB + (size_t)n * 16 * D + (ks + 1) * 32);
    }
    v8h x01[2];
    #pragma unroll
    for (int mt = 0; mt < 2; ++mt) {
      v8h zn[7];
      #pragma unroll
      for (int nb = 0; nb < 7; ++nb) {
        const int nk = nb + (nb >= i);
        zn[nb] = *(const v8h*)(zh + ((nk * NB + mt * 16 + r) * DSTR + d0));
      }
      v8h x = *(const v8h*)(zh + ((i * NB + mt * 16 + r) * DSTR + d0));
      x = (x + (zn[0] * wh[mt][0] + zn[1] * wh[mt][1]))
        + ((zn[2] * wh[mt][2] + zn[3] * wh[mt][3])
        + ((zn[4] * wh[mt][4] + zn[5] * wh[mt][5]) + zn[6] * wh[mt][6]));
      x01[mt] = x;
    }
    #pragma unroll
    for (int n = 0; n < NT; ++n) {
      acc[0][n] = __builtin_amdgcn_mfma_f32_16x16x32_f16(x01[0], dbf[n], acc[0][n], 0, 0, 0);
      acc[1][n] = __builtin_amdgcn_mfma_f32_16x16x32_f16(x01[1], dbf[n], acc[1][n], 0, 0, 0);
    }
    if (ks + 1 < KS) {
      #pragma unroll
      for (int n = 0; n < NT; ++n) dbf[n] = dbn[n];
    }
  }

  // cross-phase prefetch: next phase's B-frags fly during LN + barriers
  #pragma unroll
  for (int t = 0; t < NPRE; ++t)
    pre[t] = *(const v8h*)(preBase + (size_t)t * preStride);

  // bias + LayerNorm + relu in regs (C/D: col=n*16+r, row=mt*16+q*4+reg)
  float bv[NT], gv[NT], bev[NT];
  #pragma unroll
  for (int n = 0; n < NT; ++n) {
    const int o = n * 16 + r;
    bv[n] = bias[i * O + o]; gv[n] = g[i * O + o]; bev[n] = be[i * O + o];
  }
  #pragma unroll
  for (int mt = 0; mt < 2; ++mt) {
    #pragma unroll
    for (int reg = 0; reg < 4; ++reg) {
      float s1 = 0.f, s2 = 0.f;
      #pragma unroll
      for (int n = 0; n < NT; ++n) {
        const float h = acc[mt][n][reg] + bv[n];
        acc[mt][n][reg] = h;
        s1 += h; s2 += h * h;
      }
      #pragma unroll
      for (int mk = 1; mk < 16; mk <<= 1) { s1 += __shfl_xor(s1, mk, 16); s2 += __shfl_xor(s2, mk, 16); }
      const float mean = s1 * (1.f / O);
      const float var  = s2 * (1.f / O) - mean * mean;
      const float rs   = rsqrtf(var + EPSLN);
      #pragma unroll
      for (int n = 0; n < NT; ++n) {
        const float h = (acc[mt][n][reg] - mean) * rs * gv[n] + bev[n];
        acc[mt][n][reg] = fmaxf(h, 0.f);
      }
    }
  }
  __syncthreads();   // all waves done reading zh before overwrite
  #pragma unroll
  for (int mt = 0; mt < 2; ++mt)
    #pragma unroll
    for (int n = 0; n < NT; ++n)
      #pragma unroll
      for (int reg = 0; reg < 4; ++reg) {
        const int b = mt * 16 + q * 4 + reg;
        zh[(i * NB + b) * DSTR + n * 16 + r] = (_Float16)acc[mt][n][reg];
      }
  __syncthreads();
}

__launch_bounds__(512, 2)
__global__ void actor_mfma(KP p)
{
  __shared__ __align__(16) _Float16 zh[8 * NB * DSTR];   // [node][b][d]  135.2 KB
  __shared__ float wbuf[NB * WSTR];                      // 8.7 KB
  __shared__ float gbuf[NB * WSTR];                      // 8.7 KB
  __shared__ float xbuf[8 * NB * 4];                     // 4.0 KB

  const int i = threadIdx.x >> 6;        // wave = node
  const int u = threadIdx.x & 63;
  const int q = u >> 4, r = u & 15;
  const int bbase = blockIdx.x * NB;

  // ---- init: Z (f16) + gates; hoist gate0 weights (cover under init barrier)
  float w0g[21];
  {
    const int o8c = (u & 7) < 7 ? (u & 7) : 6;
    #pragma unroll
    for (int kd = 0; kd < 21; ++kd) w0g[kd] = p.Wg0[(i * 21 + kd) * 7 + o8c];

    #pragma unroll
    for (int c = 0; c < 2; ++c) {
      const int idx = c * 64 + u;
      if (idx < NB * 3) {
        const int b = idx / 3, d = idx - 3 * (idx / 3);
        zh[(i * NB + b) * DSTR + d] = (_Float16)p.Z[i][(size_t)(bbase + b) * 3 + d];
      }
    }
    for (int t = threadIdx.x; t < NB * 64; t += 512) {
      const int b = t >> 6, ik = t & 63;
      const int ii = ik >> 3, k = ik & 7;
      if (k < 7) {
        const int j = k + (k >= ii);
        const int gidx = (ii == 0 && j <= 3) ? j : 8 * j + ii;
        gbuf[b * WSTR + ik] = p.A[(size_t)(bbase + b) * 64 + gidx];
      }
    }
  }
  __syncthreads();

  // ================= layer 0 =================
  // gate0 (VALU, K=21)
  {
    const float bgv0 = ((u & 7) < 7) ? p.bg0[i * 7 + (u & 7)] : 0.f;
    for (int c = 0; c < NB / 8; ++c) {
      const int b = c * 8 + (u >> 3), o8 = u & 7;
      float v = -3.0e38f;
      if (o8 < 7) {
        v = bgv0;
        #pragma unroll
        for (int k = 0; k < 7; ++k) {
          const int nk = k + (k >= i);
          const _Float16* zp = zh + (nk * NB + b) * DSTR;
          v += (float)zp[0] * w0g[k * 3 + 0] + (float)zp[1] * w0g[k * 3 + 1]
             + (float)zp[2] * w0g[k * 3 + 2];
        }
      }
      float m = v;
      #pragma unroll
      for (int mk = 1; mk < 8; mk <<= 1) m = fmaxf(m, __shfl_xor(m, mk, 8));
      const float e = (o8 < 7) ? __expf(v - m) : 0.f;
      float s = e;
      #pragma unroll
      for (int mk = 1; mk < 8; mk <<= 1) s += __shfl_xor(s, mk, 8);
      if (o8 < 7) wbuf[b * WSTR + i * 8 + o8] = (e / s) * gbuf[b * WSTR + i * 8 + o8];
    }
  }
  // wbuf cols same-wave -> no barrier
  // NZ0 -> xbuf (same-wave rows; zh read-only since init barrier)
  #pragma unroll
  for (int c = 0; c < 2; ++c) {
    const int idx = c * 64 + u;
    if (idx < NB * 3) {
      const int b = idx / 3, d = idx - 3 * (idx / 3);
      float x = (float)zh[(i * NB + b) * DSTR + d];
      #pragma unroll
      for (int k = 0; k < 7; ++k) {
        const int nk = k + (k >= i);
        x += wbuf[b * WSTR + i * 8 + k] * (float)zh[(nk * NB + b) * DSTR + d];
      }
      xbuf[(i * NB + b) * 4 + d] = x;
    }
  }
  // prefetch layer-1 gate B-frags + layer0 LN params: fly during barrier + dense0
  v8h gpre1[7];
  {
    const _Float16* gb = p.WgT1 + (size_t)(i * 8 + r) * (7 * 256) + q * 8;
    #pragma unroll
    for (int nb = 0; nb < 7; ++nb) gpre1[nb] = *(const v8h*)(gb + nb * 256);
  }
  float st[17];
  #pragma unroll
  for (int s = 0; s < 17; ++s) st[s] = p.stats[i * 17 + s];
  float b0v[16], g0v[16], be0v[16];
  #pragma unroll
  for (int n = 0; n < 16; ++n) {
    const int o = n * 16 + r;
    b0v[n] = p.b0[i * 256 + o]; g0v[n] = p.g0[i * 256 + o]; be0v[n] = p.be0[i * 256 + o];
  }
  // REQUIRED barrier: dense0 overwrites zh[i][b][*] while other waves may still
  // read zh[nk=i][b][d<3] above (cross-wave WAR).
  __syncthreads();
  // dense0 via MFMA (K=3 pad 32) + analytic LN stats (no cross-lane reductions)
  {
    // per-row stats: row = mt*16 + q*4 + reg
    float mu8[8], rs8[8];
    #pragma unroll
    for (int mt = 0; mt < 2; ++mt)
      #pragma unroll
      for (int reg = 0; reg < 4; ++reg) {
        const int row = mt * 16 + q * 4 + reg;
        const float x0 = xbuf[(i * NB + row) * 4 + 0];
        const float x1 = xbuf[(i * NB + row) * 4 + 1];
        const float x2 = xbuf[(i * NB + row) * 4 + 2];
        const float mu = st[3] + x0 * st[0] + x1 * st[1] + x2 * st[2];
        const float ex2 = st[16] + 2.f * (x0 * st[13] + x1 * st[14] + x2 * st[15])
                        + x0 * (x0 * st[4] + 2.f * (x1 * st[5] + x2 * st[6]))
                        + x1 * (x1 * st[8] + 2.f * (x2 * st[9]))
                        + x2 * x2 * st[12];
        mu8[mt * 4 + reg] = mu;
        rs8[mt * 4 + reg] = rsqrtf(fmaxf(ex2 - mu * mu, 0.f) + EPSLN);
      }
    // A-frags: rows = r, k = q*8+j (nonzero only q==0, j<3)
    v8h af[2];
    #pragma unroll
    for (int j = 0; j < 8; ++j) { af[0][j] = (_Float16)0.f; af[1][j] = (_Float16)0.f; }
    if (q == 0) {
      #pragma unroll
      for (int mt = 0; mt < 2; ++mt)
        #pragma unroll
        for (int j = 0; j < 3; ++j)
          af[mt][j] = (_Float16)xbuf[(i * NB + mt * 16 + r) * 4 + j];
    }
    const _Float16* WB0 = p.W0T + (size_t)(i * 256 + r) * 32 + q * 8;
    #pragma unroll
    for (int nt = 0; nt < 16; ++nt) {
      const v8h bf = *(const v8h*)(WB0 + (size_t)nt * 16 * 32);
      const float bo = b0v[nt];
      v4f a0 = (v4f){bo, bo, bo, bo}, a1 = a0;
      a0 = __builtin_amdgcn_mfma_f32_16x16x32_f16(af[0], bf, a0, 0, 0, 0);
      a1 = __builtin_amdgcn_mfma_f32_16x16x32_f16(af[1], bf, a1, 0, 0, 0);
      const int o = nt * 16 + r;
      #pragma unroll
      for (int reg = 0; reg < 4; ++reg) {
        const float h0 = (a0[reg] - mu8[reg])     * rs8[reg]     * g0v[nt] + be0v[nt];
        const float h1 = (a1[reg] - mu8[4 + reg]) * rs8[4 + reg] * g0v[nt] + be0v[nt];
        zh[(i * NB + q * 4 + reg) * DSTR + o]      = (_Float16)fmaxf(h0, 0.f);
        zh[(i * NB + 16 + q * 4 + reg) * DSTR + o] = (_Float16)fmaxf(h1, 0.f);
      }
    }
  }
  __syncthreads();

  // ================= layers 1,2 (MFMA) with cross-phase prefetch =================
  v8h gpre2[7], wpre[2];
  mfma_layer<256, 128, 7>(zh, wbuf, gbuf, gpre1, p.WgT1, p.bg1, p.WT1, p.b1, p.g1, p.be1,
                          p.WgT2 + (size_t)(i * 8 + r) * (7 * 128) + q * 8, 128, gpre2, i, q, r);
  mfma_layer<128, 64, 2>(zh, wbuf, gbuf, gpre2, p.WgT2, p.bg2, p.WT2, p.b2, p.g2, p.be2,
                         p.WoT + (size_t)(i * 8 + r) * 64 + q * 8, 32, wpre, i, q, r);

  // ================= output 64 -> 5 via MFMA (N pad 16), fast tanh =================
  {
    const float bo = (r < 5) ? p.bout[i * 5 + r] : 0.f;
    v4f oacc[2];
    oacc[0] = (v4f){bo, bo, bo, bo}; oacc[1] = oacc[0];
    #pragma unroll
    for (int ks = 0; ks < 2; ++ks) {
      const int d0 = ks * 32 + q * 8;
      const v8h a0 = *(const v8h*)(zh + (i * NB + r) * DSTR + d0);
      const v8h a1 = *(const v8h*)(zh + (i * NB + 16 + r) * DSTR + d0);
      oacc[0] = __builtin_amdgcn_mfma_f32_16x16x32_f16(a0, wpre[ks], oacc[0], 0, 0, 0);
      oacc[1] = __builtin_amdgcn_mfma_f32_16x16x32_f16(a1, wpre[ks], oacc[1], 0, 0, 0);
    }
    if (r < 5) {
      #pragma unroll
      for (int mt = 0; mt < 2; ++mt)
        #pragma unroll
        for (int reg = 0; reg < 4; ++reg) {
          const int b = mt * 16 + q * 4 + reg;
          const float x = oacc[mt][reg];
          const float ex = __expf(2.f * x);
          p.out[((size_t)(bbase + b) * 8 + i) * 5 + r] = 1.f - 2.f / (ex + 1.f);
        }
    }
  }
}

extern "C" void kernel_launch(void* const* d_in, const int* in_sizes, int n_in,
                              void* d_out, int out_size, void* d_ws, size_t ws_size,
                              hipStream_t stream) {
  KP p;
  for (int i = 0; i < 8; ++i) p.Z[i] = (const float*)d_in[1 + i];
  p.A   = (const float*)d_in[9];
  p.W0  = (const float*)d_in[10]; p.b0 = (const float*)d_in[11];
  p.g0  = (const float*)d_in[12]; p.be0 = (const float*)d_in[13];
  p.Wg0 = (const float*)d_in[14]; p.bg0 = (const float*)d_in[15];
  const float* W1  = (const float*)d_in[16]; p.b1 = (const float*)d_in[17];
  p.g1  = (const float*)d_in[18]; p.be1 = (const float*)d_in[19];
  const float* Wg1 = (const float*)d_in[20]; p.bg1 = (const float*)d_in[21];
  const float* W2  = (const float*)d_in[22]; p.b2 = (const float*)d_in[23];
  p.g2  = (const float*)d_in[24]; p.be2 = (const float*)d_in[25];
  const float* Wg2 = (const float*)d_in[26]; p.bg2 = (const float*)d_in[27];
  const float* Wout = (const float*)d_in[28]; p.bout = (const float*)d_in[29];
  p.out = (float*)d_out;

  _Float16* wsH = (_Float16*)d_ws;
  p.WgT1 = wsH;
  p.WgT2 = wsH + E1;
  p.WoT  = wsH + E1 + E2;
  p.WT1  = wsH + E1 + E2 + E3;
  p.WT2  = wsH + E1 + E2 + E3 + E4;
  p.W0T  = wsH + E1 + E2 + E3 + E4 + E5;
  p.stats = (const float*)(wsH + E1 + E2 + E3 + E4 + E5 + E6);

  const int total = E1 + E2 + E3 + E4 + E5 + E6 + NSTAT;  // 569480
  hipLaunchKernelGGL(cvt_all, dim3((total + 255) / 256), dim3(256), 0, stream,
                     Wg1, Wg2, Wout, W1, W2, p.W0, p.b0, wsH);

  hipLaunchKernelGGL(actor_mfma, dim3(8192 / NB), dim3(512), 0, stream, p);
}

// Round 11
// 69.139 us; speedup vs baseline: 1.1768x; 1.1768x over previous
//
#include <hip/hip_runtime.h>
#include <math.h>

typedef _Float16 v8h __attribute__((ext_vector_type(8)));
typedef float    v4f __attribute__((ext_vector_type(4)));

#define NB    32       // batch elements per block (two 16-row MFMA tiles per wave)
#define DSTR  264      // zh row stride in halves
#define WSTR  68       // wbuf/gbuf per-batch stride (floats)
#define EPSLN 1e-5f

struct KP {
  const float* Z[8];
  const float* A;
  const float *W0, *b0, *g0, *be0, *Wg0, *bg0;
  const float *b1, *g1, *be1, *bg1;
  const float *b2, *g2, *be2, *bg2;
  const float *bout;
  const _Float16 *WgT1, *WgT2, *WT1, *WT2, *WoT, *W0T;
  const float *stats;   // [8][17] analytic LN stats for layer0
  float* out;
};

// ---- combined weight conversion: dst[i][o][f] = (o<Osrc) ? src[i][f][o] : 0 (f16)
__device__ __forceinline__ void cvt_one(const float* __restrict__ src, _Float16* __restrict__ dst,
                                        int F, int Osrc, int Opad, int t) {
  const int f  = t % F;
  const int io = t / F;
  const int o  = io % Opad;
  const int i  = io / Opad;
  dst[t] = (o < Osrc) ? (_Float16)src[(i * F + f) * Osrc + o] : (_Float16)0.f;
}

#define E1 114688   // Wg1 -> WgT1 (F=1792, 7->8)
#define E2 57344    // Wg2 -> WgT2 (F=896, 7->8)
#define E3 4096     // Wout -> WoT (F=64, 5->8)
#define E4 262144   // W1 -> WT1 (F=256, 128)
#define E5 65536    // W2 -> WT2 (F=128, 64)
#define E6 65536    // W0 -> W0T [i][o][k<32], k<3 = W0[d=k][o]
#define NSTAT 136   // 8 nodes x 17 f32 stats; computed 1 wave per stat

__global__ void cvt_all(const float* __restrict__ Wg1, const float* __restrict__ Wg2,
                        const float* __restrict__ Wout, const float* __restrict__ W1,
                        const float* __restrict__ W2, const float* __restrict__ W0,
                        const float* __restrict__ b0, _Float16* __restrict__ ws) {
  int t = blockIdx.x * 256 + threadIdx.x;
  if (t < E1) { cvt_one(Wg1, ws, 1792, 7, 8, t); return; }
  t -= E1;
  if (t < E2) { cvt_one(Wg2, ws + E1, 896, 7, 8, t); return; }
  t -= E2;
  if (t < E3) { cvt_one(Wout, ws + E1 + E2, 64, 5, 8, t); return; }
  t -= E3;
  if (t < E4) { cvt_one(W1, ws + E1 + E2 + E3, 256, 128, 128, t); return; }
  t -= E4;
  if (t < E5) { cvt_one(W2, ws + E1 + E2 + E3 + E4, 128, 64, 64, t); return; }
  t -= E5;
  if (t < E6) {   // W0T: t = (i*256 + o)*32 + k
    const int k = t & 31;
    const int o = (t >> 5) & 255;
    const int i = t >> 13;
    ws[E1 + E2 + E3 + E4 + E5 + t] = (k < 3) ? (_Float16)W0[(i * 3 + k) * 256 + o] : (_Float16)0.f;
    return;
  }
  t -= E6;
  // analytic LN stats, 1 WAVE per stat (region base E1+..+E6 = 569344 is
  // 256-aligned, so lanes of one stat are exactly one wave). Lane sums 4
  // strided elements, then 6-step shuffle reduce. (R10's 1-thread-256-serial
  // version cost ~13 us of prologue.)
  if (t < NSTAT * 64) {
    float* sf = (float*)(ws + E1 + E2 + E3 + E4 + E5 + E6);
    const int stat = t >> 6, lane = t & 63;
    const int i = stat / 17, j = stat % 17;
    float v = 0.f;
    #pragma unroll
    for (int c = 0; c < 4; ++c) {
      const int o = lane + c * 64;
      float e;
      if (j < 3)        e = W0[(i * 3 + j) * 256 + o];
      else if (j == 3)  e = b0[i * 256 + o];
      else if (j < 13) {
        const int a = (j - 4) / 3, bb = (j - 4) % 3;
        e = W0[(i * 3 + a) * 256 + o] * W0[(i * 3 + bb) * 256 + o];
      } else if (j < 16) {
        const int d = j - 13;
        e = W0[(i * 3 + d) * 256 + o] * b0[i * 256 + o];
      } else {
        const float x = b0[i * 256 + o]; e = x * x;
      }
      v += e;
    }
    #pragma unroll
    for (int mk = 1; mk < 64; mk <<= 1) v += __shfl_xor(v, mk, 64);
    if (lane == 0) sf[stat] = v * (1.f / 256.f);
  }
}

// One MFMA layer, M=2x16. Gate B-frags preloaded (gpre); dense ks=0 B-frags
// hoisted above gate; NPRE next-phase B-frags issued post-k-loop (fly during LN
// + barriers). wbuf cols of node i are same-wave -> no barrier after softmax.
template<int D, int O, int NPRE>
__device__ __forceinline__ void mfma_layer(
    _Float16* __restrict__ zh, float* __restrict__ wbuf, const float* __restrict__ gbuf,
    const v8h* gpre,
    const _Float16* __restrict__ WgT, const float* __restrict__ bg,
    const _Float16* __restrict__ WT, const float* __restrict__ bias,
    const float* __restrict__ g, const float* __restrict__ be,
    const _Float16* __restrict__ preBase, int preStride, v8h* pre,
    int i, int q, int r)
{
  constexpr int KS = D / 32;
  constexpr int NT = O / 16;

  const _Float16* WgB = WgT + (size_t)(i * 8 + r) * (7 * D) + q * 8;  // gate B rows
  const _Float16* WB  = WT  + (size_t)(i * O + r) * D + q * 8;        // dense B rows

  v8h dbf[NT];
  #pragma unroll
  for (int n = 0; n < NT; ++n) dbf[n] = *(const v8h*)(WB + (size_t)n * 16 * D);

  v8h gbf[7];
  #pragma unroll
  for (int nb = 0; nb < 7; ++nb) gbf[nb] = gpre[nb];

  // ---------------- gate: logits[32b x 16(7)], 4 independent chains ----------------
  v4f ca[2][2];
  #pragma unroll
  for (int mt = 0; mt < 2; ++mt)
    #pragma unroll
    for (int c = 0; c < 2; ++c) ca[mt][c] = (v4f){0.f,0.f,0.f,0.f};

  #pragma unroll
  for (int ks = 0; ks < KS; ++ks) {
    const int d0 = ks * 32 + q * 8;
    v8h gbn[7];
    if (ks + 1 < KS) {
      #pragma unroll
      for (int nb = 0; nb < 7; ++nb)
        gbn[nb] = *(const v8h*)(WgB + nb * D + (ks + 1) * 32);
    }
    #pragma unroll
    for (int nb = 0; nb < 7; ++nb) {
      const int nk = nb + (nb >= i);
      const v8h af0 = *(const v8h*)(zh + (nk * NB + r) * DSTR + d0);
      const v8h af1 = *(const v8h*)(zh + (nk * NB + 16 + r) * DSTR + d0);
      ca[0][nb & 1] = __builtin_amdgcn_mfma_f32_16x16x32_f16(af0, gbf[nb], ca[0][nb & 1], 0, 0, 0);
      ca[1][nb & 1] = __builtin_amdgcn_mfma_f32_16x16x32_f16(af1, gbf[nb], ca[1][nb & 1], 0, 0, 0);
    }
    if (ks + 1 < KS) {
      #pragma unroll
      for (int nb = 0; nb < 7; ++nb) gbf[nb] = gbn[nb];
    }
  }
  const v4f gacc[2] = { ca[0][0] + ca[0][1], ca[1][0] + ca[1][1] };

  // softmax over cols r<7 (16-lane groups), times input gates -> wbuf (same-wave cols)
  const float bgv = (r < 7) ? bg[i * 7 + r] : 0.f;
  #pragma unroll
  for (int mt = 0; mt < 2; ++mt) {
    #pragma unroll
    for (int reg = 0; reg < 4; ++reg) {
      const float v = gacc[mt][reg] + bgv;
      float m = (r < 7) ? v : -3.0e38f;
      #pragma unroll
      for (int mk = 1; mk < 16; mk <<= 1) m = fmaxf(m, __shfl_xor(m, mk, 16));
      const float e = (r < 7) ? __expf(v - m) : 0.f;
      float s = e;
      #pragma unroll
      for (int mk = 1; mk < 16; mk <<= 1) s += __shfl_xor(s, mk, 16);
      const int b = mt * 16 + q * 4 + reg;
      if (r < 7) wbuf[b * WSTR + i * 8 + r] = (e / s) * gbuf[b * WSTR + i * 8 + r];
    }
  }

  // ---------------- dense: h = (z_i + sum_k w_k z_nk) @ W_i + b ----------------
  v4f acc[2][NT];
  #pragma unroll
  for (int mt = 0; mt < 2; ++mt)
    #pragma unroll
    for (int n = 0; n < NT; ++n) acc[mt][n] = (v4f){0.f,0.f,0.f,0.f};

  _Float16 wh[2][7];
  #pragma unroll
  for (int mt = 0; mt < 2; ++mt)
    #pragma unroll
    for (int nb = 0; nb < 7; ++nb)
      wh[mt][nb] = (_Float16)wbuf[(mt * 16 + r) * WSTR + i * 8 + nb];

  #pragma unroll
  for (int ks = 0; ks < KS; ++ks) {
    const int d0 = ks * 32 + q * 8;
    v8h dbn[NT];
    if (ks + 1 < KS) {
      #pragma unroll
      for (int n = 0; n < NT; ++n)
        dbn[n] = *(const v8h*)(WB + (size_t)n * 16 * D + (ks + 1) * 32);
    }
    v8h x01[2];
    #pragma unroll
    for (int mt = 0; mt < 2; ++mt) {
      v8h zn[7];
      #pragma unroll
      for (int nb = 0; nb < 7; ++nb) {
        const int nk = nb + (nb >= i);
        zn[nb] = *(const v8h*)(zh + ((nk * NB + mt * 16 + r) * DSTR + d0));
      }
      v8h x = *(const v8h*)(zh + ((i * NB + mt * 16 + r) * DSTR + d0));
      x = (x + (zn[0] * wh[mt][0] + zn[1] * wh[mt][1]))
        + ((zn[2] * wh[mt][2] + zn[3] * wh[mt][3])
        + ((zn[4] * wh[mt][4] + zn[5] * wh[mt][5]) + zn[6] * wh[mt][6]));
      x01[mt] = x;
    }
    #pragma unroll
    for (int n = 0; n < NT; ++n) {
      acc[0][n] = __builtin_amdgcn_mfma_f32_16x16x32_f16(x01[0], dbf[n], acc[0][n], 0, 0, 0);
      acc[1][n] = __builtin_amdgcn_mfma_f32_16x16x32_f16(x01[1], dbf[n], acc[1][n], 0, 0, 0);
    }
    if (ks + 1 < KS) {
      #pragma unroll
      for (int n = 0; n < NT; ++n) dbf[n] = dbn[n];
    }
  }

  // cross-phase prefetch: next phase's B-frags fly during LN + barriers
  #pragma unroll
  for (int t = 0; t < NPRE; ++t)
    pre[t] = *(const v8h*)(preBase + (size_t)t * preStride);

  // bias + LayerNorm + relu in regs (C/D: col=n*16+r, row=mt*16+q*4+reg)
  float bv[NT], gv[NT], bev[NT];
  #pragma unroll
  for (int n = 0; n < NT; ++n) {
    const int o = n * 16 + r;
    bv[n] = bias[i * O + o]; gv[n] = g[i * O + o]; bev[n] = be[i * O + o];
  }
  #pragma unroll
  for (int mt = 0; mt < 2; ++mt) {
    #pragma unroll
    for (int reg = 0; reg < 4; ++reg) {
      float s1 = 0.f, s2 = 0.f;
      #pragma unroll
      for (int n = 0; n < NT; ++n) {
        const float h = acc[mt][n][reg] + bv[n];
        acc[mt][n][reg] = h;
        s1 += h; s2 += h * h;
      }
      #pragma unroll
      for (int mk = 1; mk < 16; mk <<= 1) { s1 += __shfl_xor(s1, mk, 16); s2 += __shfl_xor(s2, mk, 16); }
      const float mean = s1 * (1.f / O);
      const float var  = s2 * (1.f / O) - mean * mean;
      const float rs   = rsqrtf(var + EPSLN);
      #pragma unroll
      for (int n = 0; n < NT; ++n) {
        const float h = (acc[mt][n][reg] - mean) * rs * gv[n] + bev[n];
        acc[mt][n][reg] = fmaxf(h, 0.f);
      }
    }
  }
  __syncthreads();   // all waves done reading zh before overwrite
  #pragma unroll
  for (int mt = 0; mt < 2; ++mt)
    #pragma unroll
    for (int n = 0; n < NT; ++n)
      #pragma unroll
      for (int reg = 0; reg < 4; ++reg) {
        const int b = mt * 16 + q * 4 + reg;
        zh[(i * NB + b) * DSTR + n * 16 + r] = (_Float16)acc[mt][n][reg];
      }
  __syncthreads();
}

__launch_bounds__(512, 2)
__global__ void actor_mfma(KP p)
{
  __shared__ __align__(16) _Float16 zh[8 * NB * DSTR];   // [node][b][d]  135.2 KB
  __shared__ float wbuf[NB * WSTR];                      // 8.7 KB
  __shared__ float gbuf[NB * WSTR];                      // 8.7 KB
  __shared__ float xbuf[8 * NB * 4];                     // 4.0 KB

  const int i = threadIdx.x >> 6;        // wave = node
  const int u = threadIdx.x & 63;
  const int q = u >> 4, r = u & 15;
  const int bbase = blockIdx.x * NB;

  // ---- init: Z (f16) + gates; hoist gate0 weights (cover under init barrier)
  float w0g[21];
  {
    const int o8c = (u & 7) < 7 ? (u & 7) : 6;
    #pragma unroll
    for (int kd = 0; kd < 21; ++kd) w0g[kd] = p.Wg0[(i * 21 + kd) * 7 + o8c];

    #pragma unroll
    for (int c = 0; c < 2; ++c) {
      const int idx = c * 64 + u;
      if (idx < NB * 3) {
        const int b = idx / 3, d = idx - 3 * (idx / 3);
        zh[(i * NB + b) * DSTR + d] = (_Float16)p.Z[i][(size_t)(bbase + b) * 3 + d];
      }
    }
    for (int t = threadIdx.x; t < NB * 64; t += 512) {
      const int b = t >> 6, ik = t & 63;
      const int ii = ik >> 3, k = ik & 7;
      if (k < 7) {
        const int j = k + (k >= ii);
        const int gidx = (ii == 0 && j <= 3) ? j : 8 * j + ii;
        gbuf[b * WSTR + ik] = p.A[(size_t)(bbase + b) * 64 + gidx];
      }
    }
  }
  __syncthreads();

  // ================= layer 0 =================
  // gate0 (VALU, K=21)
  {
    const float bgv0 = ((u & 7) < 7) ? p.bg0[i * 7 + (u & 7)] : 0.f;
    for (int c = 0; c < NB / 8; ++c) {
      const int b = c * 8 + (u >> 3), o8 = u & 7;
      float v = -3.0e38f;
      if (o8 < 7) {
        v = bgv0;
        #pragma unroll
        for (int k = 0; k < 7; ++k) {
          const int nk = k + (k >= i);
          const _Float16* zp = zh + (nk * NB + b) * DSTR;
          v += (float)zp[0] * w0g[k * 3 + 0] + (float)zp[1] * w0g[k * 3 + 1]
             + (float)zp[2] * w0g[k * 3 + 2];
        }
      }
      float m = v;
      #pragma unroll
      for (int mk = 1; mk < 8; mk <<= 1) m = fmaxf(m, __shfl_xor(m, mk, 8));
      const float e = (o8 < 7) ? __expf(v - m) : 0.f;
      float s = e;
      #pragma unroll
      for (int mk = 1; mk < 8; mk <<= 1) s += __shfl_xor(s, mk, 8);
      if (o8 < 7) wbuf[b * WSTR + i * 8 + o8] = (e / s) * gbuf[b * WSTR + i * 8 + o8];
    }
  }
  // wbuf cols same-wave -> no barrier
  // NZ0 -> xbuf (same-wave rows; zh read-only since init barrier)
  #pragma unroll
  for (int c = 0; c < 2; ++c) {
    const int idx = c * 64 + u;
    if (idx < NB * 3) {
      const int b = idx / 3, d = idx - 3 * (idx / 3);
      float x = (float)zh[(i * NB + b) * DSTR + d];
      #pragma unroll
      for (int k = 0; k < 7; ++k) {
        const int nk = k + (k >= i);
        x += wbuf[b * WSTR + i * 8 + k] * (float)zh[(nk * NB + b) * DSTR + d];
      }
      xbuf[(i * NB + b) * 4 + d] = x;
    }
  }
  // prefetch layer-1 gate B-frags + layer0 LN params: fly during barrier + dense0
  v8h gpre1[7];
  {
    const _Float16* gb = p.WgT1 + (size_t)(i * 8 + r) * (7 * 256) + q * 8;
    #pragma unroll
    for (int nb = 0; nb < 7; ++nb) gpre1[nb] = *(const v8h*)(gb + nb * 256);
  }
  float st[17];
  #pragma unroll
  for (int s = 0; s < 17; ++s) st[s] = p.stats[i * 17 + s];
  float b0v[16], g0v[16], be0v[16];
  #pragma unroll
  for (int n = 0; n < 16; ++n) {
    const int o = n * 16 + r;
    b0v[n] = p.b0[i * 256 + o]; g0v[n] = p.g0[i * 256 + o]; be0v[n] = p.be0[i * 256 + o];
  }
  // REQUIRED barrier: dense0 overwrites zh[i][b][*] while other waves may still
  // read zh[nk=i][b][d<3] above (cross-wave WAR).
  __syncthreads();
  // dense0 via MFMA (K=3 pad 32) + analytic LN stats (no cross-lane reductions)
  {
    float mu8[8], rs8[8];
    #pragma unroll
    for (int mt = 0; mt < 2; ++mt)
      #pragma unroll
      for (int reg = 0; reg < 4; ++reg) {
        const int row = mt * 16 + q * 4 + reg;
        const float x0 = xbuf[(i * NB + row) * 4 + 0];
        const float x1 = xbuf[(i * NB + row) * 4 + 1];
        const float x2 = xbuf[(i * NB + row) * 4 + 2];
        const float mu = st[3] + x0 * st[0] + x1 * st[1] + x2 * st[2];
        const float ex2 = st[16] + 2.f * (x0 * st[13] + x1 * st[14] + x2 * st[15])
                        + x0 * (x0 * st[4] + 2.f * (x1 * st[5] + x2 * st[6]))
                        + x1 * (x1 * st[8] + 2.f * (x2 * st[9]))
                        + x2 * x2 * st[12];
        mu8[mt * 4 + reg] = mu;
        rs8[mt * 4 + reg] = rsqrtf(fmaxf(ex2 - mu * mu, 0.f) + EPSLN);
      }
    v8h af[2];
    #pragma unroll
    for (int j = 0; j < 8; ++j) { af[0][j] = (_Float16)0.f; af[1][j] = (_Float16)0.f; }
    if (q == 0) {
      #pragma unroll
      for (int mt = 0; mt < 2; ++mt)
        #pragma unroll
        for (int j = 0; j < 3; ++j)
          af[mt][j] = (_Float16)xbuf[(i * NB + mt * 16 + r) * 4 + j];
    }
    const _Float16* WB0 = p.W0T + (size_t)(i * 256 + r) * 32 + q * 8;
    #pragma unroll
    for (int nt = 0; nt < 16; ++nt) {
      const v8h bf = *(const v8h*)(WB0 + (size_t)nt * 16 * 32);
      const float bo = b0v[nt];
      v4f a0 = (v4f){bo, bo, bo, bo}, a1 = a0;
      a0 = __builtin_amdgcn_mfma_f32_16x16x32_f16(af[0], bf, a0, 0, 0, 0);
      a1 = __builtin_amdgcn_mfma_f32_16x16x32_f16(af[1], bf, a1, 0, 0, 0);
      const int o = nt * 16 + r;
      #pragma unroll
      for (int reg = 0; reg < 4; ++reg) {
        const float h0 = (a0[reg] - mu8[reg])     * rs8[reg]     * g0v[nt] + be0v[nt];
        const float h1 = (a1[reg] - mu8[4 + reg]) * rs8[4 + reg] * g0v[nt] + be0v[nt];
        zh[(i * NB + q * 4 + reg) * DSTR + o]      = (_Float16)fmaxf(h0, 0.f);
        zh[(i * NB + 16 + q * 4 + reg) * DSTR + o] = (_Float16)fmaxf(h1, 0.f);
      }
    }
  }
  __syncthreads();

  // ================= layers 1,2 (MFMA) with cross-phase prefetch =================
  v8h gpre2[7], wpre[2];
  mfma_layer<256, 128, 7>(zh, wbuf, gbuf, gpre1, p.WgT1, p.bg1, p.WT1, p.b1, p.g1, p.be1,
                          p.WgT2 + (size_t)(i * 8 + r) * (7 * 128) + q * 8, 128, gpre2, i, q, r);
  mfma_layer<128, 64, 2>(zh, wbuf, gbuf, gpre2, p.WgT2, p.bg2, p.WT2, p.b2, p.g2, p.be2,
                         p.WoT + (size_t)(i * 8 + r) * 64 + q * 8, 32, wpre, i, q, r);

  // ================= output 64 -> 5 via MFMA (N pad 16), fast tanh =================
  {
    const float bo = (r < 5) ? p.bout[i * 5 + r] : 0.f;
    v4f oacc[2];
    oacc[0] = (v4f){bo, bo, bo, bo}; oacc[1] = oacc[0];
    #pragma unroll
    for (int ks = 0; ks < 2; ++ks) {
      const int d0 = ks * 32 + q * 8;
      const v8h a0 = *(const v8h*)(zh + (i * NB + r) * DSTR + d0);
      const v8h a1 = *(const v8h*)(zh + (i * NB + 16 + r) * DSTR + d0);
      oacc[0] = __builtin_amdgcn_mfma_f32_16x16x32_f16(a0, wpre[ks], oacc[0], 0, 0, 0);
      oacc[1] = __builtin_amdgcn_mfma_f32_16x16x32_f16(a1, wpre[ks], oacc[1], 0, 0, 0);
    }
    if (r < 5) {
      #pragma unroll
      for (int mt = 0; mt < 2; ++mt)
        #pragma unroll
        for (int reg = 0; reg < 4; ++reg) {
          const int b = mt * 16 + q * 4 + reg;
          const float x = oacc[mt][reg];
          const float ex = __expf(2.f * x);
          p.out[((size_t)(bbase + b) * 8 + i) * 5 + r] = 1.f - 2.f / (ex + 1.f);
        }
    }
  }
}

extern "C" void kernel_launch(void* const* d_in, const int* in_sizes, int n_in,
                              void* d_out, int out_size, void* d_ws, size_t ws_size,
                              hipStream_t stream) {
  KP p;
  for (int i = 0; i < 8; ++i) p.Z[i] = (const float*)d_in[1 + i];
  p.A   = (const float*)d_in[9];
  p.W0  = (const float*)d_in[10]; p.b0 = (const float*)d_in[11];
  p.g0  = (const float*)d_in[12]; p.be0 = (const float*)d_in[13];
  p.Wg0 = (const float*)d_in[14]; p.bg0 = (const float*)d_in[15];
  const float* W1  = (const float*)d_in[16]; p.b1 = (const float*)d_in[17];
  p.g1  = (const float*)d_in[18]; p.be1 = (const float*)d_in[19];
  const float* Wg1 = (const float*)d_in[20]; p.bg1 = (const float*)d_in[21];
  const float* W2  = (const float*)d_in[22]; p.b2 = (const float*)d_in[23];
  p.g2  = (const float*)d_in[24]; p.be2 = (const float*)d_in[25];
  const float* Wg2 = (const float*)d_in[26]; p.bg2 = (const float*)d_in[27];
  const float* Wout = (const float*)d_in[28]; p.bout = (const float*)d_in[29];
  p.out = (float*)d_out;

  _Float16* wsH = (_Float16*)d_ws;
  p.WgT1 = wsH;
  p.WgT2 = wsH + E1;
  p.WoT  = wsH + E1 + E2;
  p.WT1  = wsH + E1 + E2 + E3;
  p.WT2  = wsH + E1 + E2 + E3 + E4;
  p.W0T  = wsH + E1 + E2 + E3 + E4 + E5;
  p.stats = (const float*)(wsH + E1 + E2 + E3 + E4 + E5 + E6);

  const int total = E1 + E2 + E3 + E4 + E5 + E6 + NSTAT * 64;  // 578048
  hipLaunchKernelGGL(cvt_all, dim3((total + 255) / 256), dim3(256), 0, stream,
                     Wg1, Wg2, Wout, W1, W2, p.W0, p.b0, wsH);

  hipLaunchKernelGGL(actor_mfma, dim3(8192 / NB), dim3(512), 0, stream, p);
}